// Round 1
// baseline (391.943 us; speedup 1.0000x reference)
//
#include <hip/hip_runtime.h>
#include <hip/hip_bf16.h>

// Problem: VQ-VAE vector quantizer, B=32,C=64,H=64,W=64, K=512 codes, DECAY=0.99, EPS=1e-5
// N = B*H*W = 131072 vectors of dim 64.
// Outputs (fp32, concat): out[8388608], commitment_loss[1], unique_codes[1], new_codebook[32768]

#define NROWS 2048            // B*H rows; one wave per row, lane = w
#define KCODES 512
#define CDIM 64
#define SLAB_STRIDE 33792     // floats per block slab: 32768 sums + 512 counts + 1 loss + pad
#define LDS_FLOATS 33800      // max(phase1: 32768 cb + 512 esq, phase2: 512*65 sums + 512 hist) + 8 red
#define NSLAB_FAST 256

__global__ void __launch_bounds__(512, 2)
vq_assign(const float* __restrict__ x, const float* __restrict__ cbg,
          float* __restrict__ out, float* __restrict__ slab_base, int atomic_mode) {
    extern __shared__ float lds[];
    float* cb  = lds;            // [0, 32768) codebook, phase 1
    float* esq = lds + 32768;    // [32768, 33280) |e|^2, phase 1
    const int tid  = threadIdx.x;
    const int lane = tid & 63;
    const int wv   = tid >> 6;   // 0..7

    // ---- stage codebook into LDS (coalesced float4) ----
    {
        const float4* src = (const float4*)cbg;
        float4* dst = (float4*)cb;
        #pragma unroll 4
        for (int i = tid; i < 8192; i += 512) dst[i] = src[i];
    }
    __syncthreads();

    // ---- per-code squared norms (rotated reads -> conflict-free) ----
    {
        float s = 0.f;
        const float* rowp = cb + (tid << 6);
        #pragma unroll
        for (int c = 0; c < 64; ++c) { float v = rowp[(tid + c) & 63]; s = fmaf(v, v, s); }
        esq[tid] = s;
    }
    __syncthreads();

    // ---- load this lane's x vector (coalesced: 64 x 256B wave transactions) ----
    const int row = blockIdx.x * 8 + wv;   // 0..2047
    const int bb = row >> 6, hh = row & 63;
    const long base = (long)bb * 262144 + (long)hh * 64 + lane;
    float xv[64];
    #pragma unroll
    for (int c = 0; c < 64; ++c) xv[c] = x[base + (long)c * 4096];

    // ---- argmin over 512 codes: score = |e|^2 - 2 x.e  (x_sq constant per row) ----
    float best = 3.4e38f; int bk = 0;
    for (int k = 0; k < KCODES; k += 2) {
        const float4* e0 = (const float4*)(cb + (k << 6));
        const float4* e1 = (const float4*)(cb + ((k + 1) << 6));
        float a0=0.f,a1=0.f,a2=0.f,a3=0.f,b0=0.f,b1=0.f,b2=0.f,b3=0.f;
        #pragma unroll
        for (int j = 0; j < 16; ++j) {
            float4 ea = e0[j];
            float4 eb = e1[j];
            a0 = fmaf(xv[4*j+0], ea.x, a0);
            a1 = fmaf(xv[4*j+1], ea.y, a1);
            a2 = fmaf(xv[4*j+2], ea.z, a2);
            a3 = fmaf(xv[4*j+3], ea.w, a3);
            b0 = fmaf(xv[4*j+0], eb.x, b0);
            b1 = fmaf(xv[4*j+1], eb.y, b1);
            b2 = fmaf(xv[4*j+2], eb.z, b2);
            b3 = fmaf(xv[4*j+3], eb.w, b3);
        }
        float s0 = esq[k]     - 2.f * ((a0 + a1) + (a2 + a3));
        float s1 = esq[k + 1] - 2.f * ((b0 + b1) + (b2 + b3));
        if (s0 < best) { best = s0; bk = k; }       // strict <, ascending k: first-min
        if (s1 < best) { best = s1; bk = k + 1; }
    }

    // ---- quantized output + commitment loss partial (q gathered from GLOBAL codebook:
    //      avoids 64-way LDS bank conflicts of divergent same-column LDS reads) ----
    float lsum = 0.f;
    const float* qg = cbg + (bk << 6);
    #pragma unroll
    for (int c = 0; c < 64; ++c) {
        float qc = qg[c];
        float xc = xv[c];
        out[base + (long)c * 4096] = xc + (qc - xc);  // straight-through value == q (ref arithmetic)
        float d = xc - qc;
        lsum = fmaf(d, d, lsum);
    }
    #pragma unroll
    for (int o = 32; o > 0; o >>= 1) lsum += __shfl_down(lsum, o, 64);

    // ---- phase 2: repurpose LDS as per-block segment-sum accumulator ----
    __syncthreads();                 // everyone done reading cb/esq
    float* sums = lds;               // [0, 33280) : 512 codes x 65-padded
    float* hist = lds + 33280;       // [33280, 33792)
    float* red  = lds + 33792;       // [33792, 33800)
    #pragma unroll 4
    for (int i = tid; i < 33792; i += 512) lds[i] = 0.f;
    __syncthreads();

    const int sb = bk * 65;          // 65-pad: bank = (bk + c) % 32 -> spread by code
    #pragma unroll
    for (int c = 0; c < 64; ++c) atomicAdd(&sums[sb + c], xv[c]);
    atomicAdd(&hist[bk], 1.0f);
    if (lane == 0) red[wv] = lsum;
    __syncthreads();

    // ---- flush to global slab ----
    if (atomic_mode) {
        float* slab = slab_base;     // single shared slab, atomics (small-ws fallback)
        for (int i = tid; i < 32768; i += 512) {
            float v = sums[(i >> 6) * 65 + (i & 63)];
            if (v != 0.f) atomicAdd(&slab[i], v);
        }
        { float v = hist[tid]; if (v != 0.f) atomicAdd(&slab[32768 + tid], v); }
        if (tid == 0) {
            float l = 0.f;
            #pragma unroll
            for (int i = 0; i < 8; ++i) l += red[i];
            atomicAdd(&slab[33280], l);
        }
    } else {
        float* slab = slab_base + (long)blockIdx.x * SLAB_STRIDE;
        #pragma unroll 4
        for (int i = tid; i < 32768; i += 512)
            slab[i] = sums[(i >> 6) * 65 + (i & 63)];   // LDS read conflict-free, store coalesced
        slab[32768 + tid] = hist[tid];
        if (tid == 0) {
            float l = 0.f;
            #pragma unroll
            for (int i = 0; i < 8; ++i) l += red[i];
            slab[33280] = l;
        }
    }
}

__global__ void __launch_bounds__(512)
vq_scalars(const float* __restrict__ slab_base, const float* __restrict__ ema_cs,
           float* __restrict__ smoothed, float* __restrict__ out_scalars, int nslab) {
    __shared__ float s_red[32];
    const int tid = threadIdx.x;     // tid == code k (512 threads)
    float cnt = 0.f;
    #pragma unroll 8
    for (int s = 0; s < nslab; ++s) cnt += slab_base[(long)s * SLAB_STRIDE + 32768 + tid];
    float ncs = 0.99f * ema_cs[tid] + 0.01f * cnt;

    float v1 = ncs;                                   // -> n
    float v2 = (cnt > 0.f) ? 1.f : 0.f;               // -> unique_codes
    float v3 = (tid < nslab) ? slab_base[(long)tid * SLAB_STRIDE + 33280] : 0.f;  // -> loss sum
    #pragma unroll
    for (int o = 32; o > 0; o >>= 1) {
        v1 += __shfl_down(v1, o, 64);
        v2 += __shfl_down(v2, o, 64);
        v3 += __shfl_down(v3, o, 64);
    }
    const int wv = tid >> 6;
    if ((tid & 63) == 0) { s_red[wv] = v1; s_red[wv + 8] = v2; s_red[wv + 16] = v3; }
    __syncthreads();
    if (tid == 0) {
        float n = 0.f, uq = 0.f, l = 0.f;
        #pragma unroll
        for (int i = 0; i < 8; ++i) { n += s_red[i]; uq += s_red[i + 8]; l += s_red[i + 16]; }
        s_red[24] = n;
        out_scalars[0] = l / 8388608.f;   // commitment_loss = mean over B*C*H*W
        out_scalars[1] = uq;              // unique_codes
    }
    __syncthreads();
    float n = s_red[24];
    smoothed[tid] = (ncs + 1e-5f) / (n + 512.f * 1e-5f) * n;
}

__global__ void __launch_bounds__(256)
vq_codebook(const float* __restrict__ slab_base, const float* __restrict__ ema_w,
            const float* __restrict__ smoothed, float* __restrict__ out_cb, int nslab) {
    const int e = blockIdx.x * 256 + threadIdx.x;     // 0..32767
    float s = 0.f;
    #pragma unroll 8
    for (int sl = 0; sl < nslab; ++sl) s += slab_base[(long)sl * SLAB_STRIDE + e];
    float nw = 0.99f * ema_w[e] + 0.01f * s;
    out_cb[e] = nw / smoothed[e >> 6];
}

extern "C" void kernel_launch(void* const* d_in, const int* in_sizes, int n_in,
                              void* d_out, int out_size, void* d_ws, size_t ws_size,
                              hipStream_t stream) {
    const float* x      = (const float*)d_in[0];   // 32*64*64*64
    const float* cb     = (const float*)d_in[1];   // 512*64
    const float* ema_cs = (const float*)d_in[2];   // 512
    const float* ema_w  = (const float*)d_in[3];   // 512*64

    float* out        = (float*)d_out;
    float* scalars    = out + 8388608;             // [loss, unique]
    float* out_cb     = out + 8388610;             // 512*64
    float* ws         = (float*)d_ws;

    const size_t fast_bytes = ((size_t)NSLAB_FAST * SLAB_STRIDE + 512) * sizeof(float);
    int nslab, atomic_mode;
    if (ws_size >= fast_bytes) { nslab = NSLAB_FAST; atomic_mode = 0; }
    else                       { nslab = 1;          atomic_mode = 1; }

    float* smoothed = ws + (size_t)nslab * SLAB_STRIDE;

    if (atomic_mode) {
        // fallback path needs a zeroed shared slab every call
        hipMemsetAsync(d_ws, 0, (size_t)SLAB_STRIDE * sizeof(float), stream);
    }

    const size_t lds_bytes = (size_t)LDS_FLOATS * sizeof(float);  // 135200 B (<160 KiB)
    vq_assign<<<256, 512, lds_bytes, stream>>>(x, cb, out, ws, atomic_mode);
    vq_scalars<<<1, 512, 0, stream>>>(ws, ema_cs, smoothed, scalars, nslab);
    vq_codebook<<<128, 256, 0, stream>>>(ws, ema_w, smoothed, out_cb, nslab);
}

// Round 2
// 255.792 us; speedup vs baseline: 1.5323x; 1.5323x over previous
//
#include <hip/hip_runtime.h>

// VQ-VAE vector quantizer: B=32,C=64,H=64,W=64, K=512, DECAY=0.99, EPS=1e-5
// N = 131072 vectors of dim 64. One LANE per vector (lane = w), 2 waves per row
// splitting the 512 codes. Codebook delivered via SMEM (s_load) -> no LDS traffic
// in the hot loop (R1 was ds_read_b128-throughput-bound at 13.7 cyc/read).

#define AS4 __attribute__((address_space(4)))
#define KCODES 512
#define SLAB_STRIDE 33792     // per-block slab: 32768 sums + 512 counts + 1 loss + pad
#define NSLAB_FAST 256

// LDS layout (floats)
#define OFF_SUMS 0            // 512*65 = 33280 (65-pad: conflict-free)
#define OFF_HIST 33280        // 512
#define OFF_RED  33792        // 16
#define OFF_MB   33808        // 16*64 merge best
#define OFF_MBK  34832        // 16*64 merge bk
#define LDS_FLOATS 35856      // 143,424 B < 160 KiB

__global__ void __launch_bounds__(512)
vq_esq(const float* __restrict__ cb, float* __restrict__ esq) {
    const int k = threadIdx.x;            // 512
    const float* r = cb + (k << 6);
    float s = 0.f;
    #pragma unroll
    for (int c = 0; c < 64; ++c) { float v = r[c]; s = fmaf(v, v, s); }
    esq[k] = s;
}

__global__ void __launch_bounds__(1024, 4)
vq_assign(const float* __restrict__ x, const float* __restrict__ cbg,
          const float* __restrict__ esqg, float* __restrict__ out,
          float* __restrict__ slab_base, int atomic_mode) {
    extern __shared__ float lds[];
    const int tid  = threadIdx.x;
    const int lane = tid & 63;
    const int wv   = tid >> 6;                 // 0..15
    // wave-uniform code partition (readfirstlane: force uniformity for SMEM selection)
    const int kpart = __builtin_amdgcn_readfirstlane((int)((threadIdx.x >> 6) & 1));
    const int kbase = kpart << 8;              // 0 or 256

    // constant-address-space views -> guaranteed s_load for uniform indices (CK idiom)
    const AS4 float* cbc  = (const AS4 float*)(size_t)cbg;
    const AS4 float* esqc = (const AS4 float*)(size_t)esqg;

    // ---- load this lane's x vector (coalesced 256B wave transactions) ----
    const int row = blockIdx.x * 8 + (wv >> 1);   // 0..2047  (row = b*64 + h)
    const int bb = row >> 6, hh = row & 63;
    const long base = (long)bb * 262144 + (long)hh * 64 + lane;
    float xv[64];
    #pragma unroll
    for (int c = 0; c < 64; ++c) xv[c] = x[base + (long)c * 4096];

    // ---- argmin over this wave's 256 codes: score = |e|^2 - 2 x.e ----
    float best = 3.4e38f; int bk = kbase;
    #pragma unroll 2
    for (int kk = 0; kk < 256; ++kk) {
        const int k = kbase + kk;
        const AS4 float* e = cbc + ((long)k << 6);
        float a0 = 0.f, a1 = 0.f, a2 = 0.f, a3 = 0.f;
        #pragma unroll
        for (int j = 0; j < 16; ++j) {
            a0 = fmaf(xv[4*j+0], e[4*j+0], a0);
            a1 = fmaf(xv[4*j+1], e[4*j+1], a1);
            a2 = fmaf(xv[4*j+2], e[4*j+2], a2);
            a3 = fmaf(xv[4*j+3], e[4*j+3], a3);
        }
        float s = esqc[k] - 2.f * ((a0 + a1) + (a2 + a3));
        if (s < best) { best = s; bk = k; }    // strict <, ascending k: first-min
    }

    // ---- merge the two k-partitions per lane (A = codes 0..255 wins ties) ----
    float* mb = lds + OFF_MB;
    int*   mk = (int*)(lds + OFF_MBK);
    mb[wv * 64 + lane] = best;
    mk[wv * 64 + lane] = bk;
    __syncthreads();
    {
        const int p = (wv ^ 1) * 64 + lane;
        float ob = mb[p]; int obk = mk[p];
        if (kpart == 0) { if (ob <  best) { best = ob; bk = obk; } }
        else            { if (ob <= best) { best = ob; bk = obk; } }
    }

    // ---- zero phase-2 accumulator (doesn't overlap merge arrays) ----
    #pragma unroll 4
    for (int i = tid; i < 33792; i += 1024) lds[i] = 0.f;

    // ---- quantized output + commitment loss, split: wave A does c<32, B c>=32 ----
    const int ch = kpart << 5;
    float lsum = 0.f;
    {
        const float* qg = cbg + ((long)bk << 6) + ch;   // divergent gather (L1/L2-hot)
        #pragma unroll
        for (int c = 0; c < 32; ++c) {
            float qc = qg[c];
            float xc = xv[ch + c];
            out[base + (long)(ch + c) * 4096] = xc + (qc - xc);  // ref arithmetic
            float d = xc - qc;
            lsum = fmaf(d, d, lsum);
        }
    }
    #pragma unroll
    for (int o = 32; o > 0; o >>= 1) lsum += __shfl_down(lsum, o, 64);

    // ---- phase 2: per-block segment sums in LDS ----
    float* sums = lds + OFF_SUMS;
    float* hist = lds + OFF_HIST;
    float* red  = lds + OFF_RED;
    __syncthreads();                       // zero complete
    const int sb = bk * 65 + ch;           // 65-pad spreads codes across banks
    #pragma unroll
    for (int c = 0; c < 32; ++c) atomicAdd(&sums[sb + c], xv[ch + c]);
    if (kpart == 0) atomicAdd(&hist[bk], 1.0f);
    if (lane == 0) red[wv] = lsum;
    __syncthreads();

    // ---- flush to global slab ----
    if (atomic_mode) {
        float* slab = slab_base;
        for (int i = tid; i < 32768; i += 1024) {
            float v = sums[(i >> 6) * 65 + (i & 63)];
            if (v != 0.f) atomicAdd(&slab[i], v);
        }
        if (tid < 512) { float v = hist[tid]; if (v != 0.f) atomicAdd(&slab[32768 + tid], v); }
        if (tid == 0) {
            float l = 0.f;
            #pragma unroll
            for (int i = 0; i < 16; ++i) l += red[i];
            atomicAdd(&slab[33280], l);
        }
    } else {
        float* slab = slab_base + (long)blockIdx.x * SLAB_STRIDE;
        #pragma unroll 4
        for (int i = tid; i < 32768; i += 1024)
            slab[i] = sums[(i >> 6) * 65 + (i & 63)];   // conflict-free read, coalesced store
        if (tid < 512) slab[32768 + tid] = hist[tid];
        if (tid == 0) {
            float l = 0.f;
            #pragma unroll
            for (int i = 0; i < 16; ++i) l += red[i];
            slab[33280] = l;
        }
    }
}

__global__ void __launch_bounds__(512)
vq_scalars(const float* __restrict__ slab_base, const float* __restrict__ ema_cs,
           float* __restrict__ smoothed, float* __restrict__ out_scalars, int nslab) {
    __shared__ float s_red[32];
    const int tid = threadIdx.x;          // tid == code k
    float cnt = 0.f;
    #pragma unroll 8
    for (int s = 0; s < nslab; ++s) cnt += slab_base[(long)s * SLAB_STRIDE + 32768 + tid];
    float ncs = 0.99f * ema_cs[tid] + 0.01f * cnt;

    float v1 = ncs;                                    // -> n
    float v2 = (cnt > 0.f) ? 1.f : 0.f;                // -> unique_codes
    float v3 = (tid < nslab) ? slab_base[(long)tid * SLAB_STRIDE + 33280] : 0.f;  // loss
    #pragma unroll
    for (int o = 32; o > 0; o >>= 1) {
        v1 += __shfl_down(v1, o, 64);
        v2 += __shfl_down(v2, o, 64);
        v3 += __shfl_down(v3, o, 64);
    }
    const int wv = tid >> 6;
    if ((tid & 63) == 0) { s_red[wv] = v1; s_red[wv + 8] = v2; s_red[wv + 16] = v3; }
    __syncthreads();
    if (tid == 0) {
        float n = 0.f, uq = 0.f, l = 0.f;
        #pragma unroll
        for (int i = 0; i < 8; ++i) { n += s_red[i]; uq += s_red[i + 8]; l += s_red[i + 16]; }
        s_red[24] = n;
        out_scalars[0] = l / 8388608.f;
        out_scalars[1] = uq;
    }
    __syncthreads();
    float n = s_red[24];
    smoothed[tid] = (ncs + 1e-5f) / (n + 512.f * 1e-5f) * n;
}

__global__ void __launch_bounds__(256)
vq_codebook(const float* __restrict__ slab_base, const float* __restrict__ ema_w,
            const float* __restrict__ smoothed, float* __restrict__ out_cb, int nslab) {
    const int e = blockIdx.x * 256 + threadIdx.x;      // 0..32767
    float s = 0.f;
    #pragma unroll 8
    for (int sl = 0; sl < nslab; ++sl) s += slab_base[(long)sl * SLAB_STRIDE + e];
    float nw = 0.99f * ema_w[e] + 0.01f * s;
    out_cb[e] = nw / smoothed[e >> 6];
}

extern "C" void kernel_launch(void* const* d_in, const int* in_sizes, int n_in,
                              void* d_out, int out_size, void* d_ws, size_t ws_size,
                              hipStream_t stream) {
    const float* x      = (const float*)d_in[0];
    const float* cb     = (const float*)d_in[1];
    const float* ema_cs = (const float*)d_in[2];
    const float* ema_w  = (const float*)d_in[3];

    float* out     = (float*)d_out;
    float* scalars = out + 8388608;
    float* out_cb  = out + 8388610;
    float* ws      = (float*)d_ws;

    const size_t fast_bytes = ((size_t)NSLAB_FAST * SLAB_STRIDE + 1024) * sizeof(float);
    int nslab, atomic_mode;
    if (ws_size >= fast_bytes) { nslab = NSLAB_FAST; atomic_mode = 0; }
    else                       { nslab = 1;          atomic_mode = 1; }

    float* smoothed = ws + (size_t)nslab * SLAB_STRIDE;
    float* esq      = smoothed + 512;

    if (atomic_mode) {
        hipMemsetAsync(d_ws, 0, (size_t)SLAB_STRIDE * sizeof(float), stream);
    }

    vq_esq<<<1, 512, 0, stream>>>(cb, esq);
    const size_t lds_bytes = (size_t)LDS_FLOATS * sizeof(float);
    vq_assign<<<256, 1024, lds_bytes, stream>>>(x, cb, esq, out, ws, atomic_mode);
    vq_scalars<<<1, 512, 0, stream>>>(ws, ema_cs, smoothed, scalars, nslab);
    vq_codebook<<<128, 256, 0, stream>>>(ws, ema_w, smoothed, out_cb, nslab);
}

// Round 3
// 150.666 us; speedup vs baseline: 2.6014x; 1.6977x over previous
//
#include <hip/hip_runtime.h>

// VQ-VAE vector quantizer: B=32,C=64,H=64,W=64, K=512, DECAY=0.99, EPS=1e-5
// N = 131072 vectors, dim 64.
// R3: distances via mfma_f32_32x32x16_bf16 with 4-term hi/lo split (codes=A rows,
// x=B cols -> argmin is lane-local). Codes stream from global fragment-major bf16
// (L1/L2-hot, VMEM pipe); x fragments resident in VGPRs. Top-2 + exact-fp32 refine
// for near-ties (gap<1e-3) keeps argmin in the R2-proven numerical regime.

typedef __attribute__((ext_vector_type(8))) short bf16x8;
typedef __attribute__((ext_vector_type(16))) float f32x16;

#define KCODES 512
#define SLAB_STRIDE 33792     // per-block slab: 32768 sums + 512 counts + 1 loss + pad
#define NSLAB_FAST 256

// LDS layout (floats). Phase1: x-stage [0,32768) (512 rows x 256B, hi|lo, swizzled).
// Phase2: sums 512x65. ESQ/BK survive both phases.
#define OFF_HIST 33280
#define OFF_RED  33792        // 16
#define OFF_ESQ  33808        // 512
#define OFF_BK1  34320        // 512
#define OFF_BK2  34832        // 512
#define LDS_FLOATS 35344      // 141,376 B < 160 KiB

#define MFMA32 __builtin_amdgcn_mfma_f32_32x32x16_bf16

__device__ __forceinline__ unsigned short f2bf(float f) {
    unsigned u = __float_as_uint(f);
    return (unsigned short)((u + 0x7fffu + ((u >> 16) & 1u)) >> 16);
}
__device__ __forceinline__ float bf2f(unsigned short h) {
    return __uint_as_float(((unsigned)h) << 16);
}

// ---- prep: esq (exact R2 formula) + fragment-major bf16 hi/lo codebook ----
// cbF unit u = (cs*2+hh)*512 + k, 32 bytes: [hi bf16x8 | lo bf16x8], c = cs*16+hh*8+j
__global__ void __launch_bounds__(512)
vq_prep(const float* __restrict__ cb, float* __restrict__ esq, char* __restrict__ cbF) {
    const int k = threadIdx.x;
    float v[64];
    float s = 0.f;
    #pragma unroll
    for (int c = 0; c < 64; ++c) { v[c] = cb[(k << 6) + c]; s = fmaf(v[c], v[c], s); }
    esq[k] = s;
    #pragma unroll
    for (int cs = 0; cs < 4; ++cs) {
        #pragma unroll
        for (int hh = 0; hh < 2; ++hh) {
            bf16x8 h8, l8;
            #pragma unroll
            for (int j = 0; j < 8; ++j) {
                float e = v[cs * 16 + hh * 8 + j];
                unsigned short hb = f2bf(e);
                float lo = e - bf2f(hb);
                h8[j] = (short)hb;
                l8[j] = (short)f2bf(lo);
            }
            char* p = cbF + (size_t)(((cs * 2 + hh) * 512 + k) * 32);
            *(bf16x8*)p = h8;
            *(bf16x8*)(p + 16) = l8;
        }
    }
}

__device__ __forceinline__ void loadA(const char* __restrict__ cbF, int hh, int code,
                                      bf16x8* A) {
    #pragma unroll
    for (int cs = 0; cs < 4; ++cs) {
        const char* p = cbF + (size_t)(((cs * 2 + hh) * 512 + code) * 32);
        A[2 * cs]     = *(const bf16x8*)p;        // hi
        A[2 * cs + 1] = *(const bf16x8*)(p + 16); // lo
    }
}

// top-2 update; kq is wave-uniform (SGPR), strict < keeps first (ascending kq)
__device__ __forceinline__ void upd(float s, int kq, float& b1, int& q1, float& b2, int& q2) {
    bool t1 = s < b1;
    bool t2 = s < b2;
    float nb2 = t1 ? b1 : (t2 ? s : b2);
    int   nq2 = t1 ? q1 : (t2 ? kq : q2);
    b2 = nb2; q2 = nq2;
    b1 = t1 ? s : b1;
    q1 = t1 ? kq : q1;
}

__global__ void __launch_bounds__(512, 1)
vq_assign(const float* __restrict__ x, const float* __restrict__ cbg,
          const float* __restrict__ esqg, const char* __restrict__ cbF,
          float* __restrict__ out, float* __restrict__ slab_base, int atomic_mode) {
    extern __shared__ float lds[];
    float* esq  = lds + OFF_ESQ;
    int*   bki1 = (int*)(lds + OFF_BK1);
    int*   bki2 = (int*)(lds + OFF_BK2);
    const int tid  = threadIdx.x;
    const int lane = tid & 63;
    const int wv   = tid >> 6;        // 0..7
    const int l31  = lane & 31;
    const int hh   = lane >> 5;       // k-half
    const int n0   = blockIdx.x * 512;

    // ---- stage esq + x (hi|lo 256B rows, XOR-swizzled) ----
    esq[tid] = esqg[tid];
    {
        const int n  = n0 + tid;                      // n_local == tid
        const int bb = n >> 12, h = (n >> 6) & 63;
        const long gx = (long)bb * 262144 + (long)h * 64 + (n & 63);
        char* rowp = (char*)lds + tid * 256;
        const int sw = (tid & 15) << 4;
        #pragma unroll
        for (int cc = 0; cc < 8; ++cc) {
            float v[8];
            #pragma unroll
            for (int j = 0; j < 8; ++j) v[j] = x[gx + (long)(cc * 8 + j) * 4096];
            bf16x8 h8, l8;
            #pragma unroll
            for (int j = 0; j < 8; ++j) {
                float m2 = -2.f * v[j];
                unsigned short hb = f2bf(m2);
                float lo = m2 - bf2f(hb);     // exact (Sterbenz)
                h8[j] = (short)hb;
                l8[j] = (short)f2bf(lo);
            }
            *(bf16x8*)(rowp + ((cc * 16) ^ sw))       = h8;
            *(bf16x8*)(rowp + ((128 + cc * 16) ^ sw)) = l8;
        }
    }
    __syncthreads();

    // ---- load resident B fragments (x): 2 coltiles x 4 csteps x hi/lo ----
    bf16x8 B0h[4], B0l[4], B1h[4], B1l[4];
    {
        #pragma unroll
        for (int ct = 0; ct < 2; ++ct) {
            const int nl = wv * 64 + ct * 32 + l31;
            const char* rowp = (const char*)lds + nl * 256;
            const int sw = (nl & 15) << 4;
            #pragma unroll
            for (int cs = 0; cs < 4; ++cs) {
                int oh = (cs * 32 + hh * 16) ^ sw;
                int ol = (128 + cs * 32 + hh * 16) ^ sw;
                if (ct == 0) { B0h[cs] = *(const bf16x8*)(rowp + oh); B0l[cs] = *(const bf16x8*)(rowp + ol); }
                else         { B1h[cs] = *(const bf16x8*)(rowp + oh); B1l[cs] = *(const bf16x8*)(rowp + ol); }
            }
        }
    }

    // ---- K loop: 16 tiles of 32 codes, 2-deep A prefetch ----
    float b1[2] = {3.4e38f, 3.4e38f}, b2[2] = {3.4e38f, 3.4e38f};
    int   q1[2] = {0, 0},             q2[2] = {0, 0};
    bf16x8 A0[8], A1[8];
    loadA(cbF, hh, l31, A0);
    #pragma unroll 1
    for (int kt = 0; kt < 16; kt += 2) {
        loadA(cbF, hh, (kt + 1) * 32 + l31, A1);
        {
            f32x16 acc0 = {}; f32x16 acc1 = {};
            #pragma unroll
            for (int cs = 0; cs < 4; ++cs) {
                acc0 = MFMA32(A0[2*cs],   B0h[cs], acc0, 0, 0, 0);
                acc0 = MFMA32(A0[2*cs+1], B0h[cs], acc0, 0, 0, 0);
                acc0 = MFMA32(A0[2*cs],   B0l[cs], acc0, 0, 0, 0);
                acc0 = MFMA32(A0[2*cs+1], B0l[cs], acc0, 0, 0, 0);
                acc1 = MFMA32(A0[2*cs],   B1h[cs], acc1, 0, 0, 0);
                acc1 = MFMA32(A0[2*cs+1], B1h[cs], acc1, 0, 0, 0);
                acc1 = MFMA32(A0[2*cs],   B1l[cs], acc1, 0, 0, 0);
                acc1 = MFMA32(A0[2*cs+1], B1l[cs], acc1, 0, 0, 0);
            }
            #pragma unroll
            for (int g = 0; g < 4; ++g) {
                float4 e4 = *(const float4*)(esq + kt * 32 + 4 * hh + 8 * g);
                const float ev[4] = {e4.x, e4.y, e4.z, e4.w};
                #pragma unroll
                for (int r = 0; r < 4; ++r) {
                    int kq = kt * 32 + 8 * g + r;          // hh-free, wave-uniform
                    upd(ev[r] + acc0[4*g+r], kq, b1[0], q1[0], b2[0], q2[0]);
                    upd(ev[r] + acc1[4*g+r], kq, b1[1], q1[1], b2[1], q2[1]);
                }
            }
        }
        if (kt + 2 < 16) loadA(cbF, hh, (kt + 2) * 32 + l31, A0);
        {
            f32x16 acc0 = {}; f32x16 acc1 = {};
            #pragma unroll
            for (int cs = 0; cs < 4; ++cs) {
                acc0 = MFMA32(A1[2*cs],   B0h[cs], acc0, 0, 0, 0);
                acc0 = MFMA32(A1[2*cs+1], B0h[cs], acc0, 0, 0, 0);
                acc0 = MFMA32(A1[2*cs],   B0l[cs], acc0, 0, 0, 0);
                acc0 = MFMA32(A1[2*cs+1], B0l[cs], acc0, 0, 0, 0);
                acc1 = MFMA32(A1[2*cs],   B1h[cs], acc1, 0, 0, 0);
                acc1 = MFMA32(A1[2*cs+1], B1h[cs], acc1, 0, 0, 0);
                acc1 = MFMA32(A1[2*cs],   B1l[cs], acc1, 0, 0, 0);
                acc1 = MFMA32(A1[2*cs+1], B1l[cs], acc1, 0, 0, 0);
            }
            #pragma unroll
            for (int g = 0; g < 4; ++g) {
                float4 e4 = *(const float4*)(esq + (kt + 1) * 32 + 4 * hh + 8 * g);
                const float ev[4] = {e4.x, e4.y, e4.z, e4.w};
                #pragma unroll
                for (int r = 0; r < 4; ++r) {
                    int kq = (kt + 1) * 32 + 8 * g + r;
                    upd(ev[r] + acc0[4*g+r], kq, b1[0], q1[0], b2[0], q2[0]);
                    upd(ev[r] + acc1[4*g+r], kq, b1[1], q1[1], b2[1], q2[1]);
                }
            }
        }
    }

    // ---- merge lane-halves (true k = kq + 4*hh), write per-x winner(+runner) ----
    #pragma unroll
    for (int ct = 0; ct < 2; ++ct) {
        float mb1 = b1[ct], mb2 = b2[ct];
        int   mk1 = q1[ct] + 4 * hh, mk2 = q2[ct] + 4 * hh;
        float ob1 = __shfl_xor(mb1, 32, 64); int ok1 = __shfl_xor(mk1, 32, 64);
        float ob2 = __shfl_xor(mb2, 32, 64); int ok2 = __shfl_xor(mk2, 32, 64);
        bool t = (ob1 < mb1) || (ob1 == mb1 && ok1 < mk1);
        float w1 = t ? ob1 : mb1;  int wk1 = t ? ok1 : mk1;
        float l1 = t ? mb1 : ob1;  int lk1 = t ? mk1 : ok1;   // loser of firsts
        float w2c = t ? ob2 : mb2; int wk2c = t ? ok2 : mk2;  // winner's second
        bool t2 = (w2c < l1) || (w2c == l1 && wk2c < lk1);
        float w2 = t2 ? w2c : l1;  int wk2 = t2 ? wk2c : lk1;
        if (hh == 0) {
            int nl = wv * 64 + ct * 32 + l31;
            bki1[nl] = wk1;
            bki2[nl] = (w2 - w1 < 1e-3f) ? wk2 : wk1;   // refine only near-ties
        }
    }
    __syncthreads();

    // ---- zero phase-2 accumulators ----
    float* sums = lds;                 // 512 x 65
    float* hist = lds + OFF_HIST;
    float* red  = lds + OFF_RED;
    #pragma unroll 4
    for (int i = tid; i < 33792; i += 512) lds[i] = 0.f;
    __syncthreads();

    // ---- phase 2: refine + out + loss + segment sums (lane = w, R2-proven) ----
    {
        const int nl = wv * 64 + lane;
        const int n  = n0 + nl;
        const int bb = n >> 12, h = (n >> 6) & 63;
        const long gx = (long)bb * 262144 + (long)h * 64 + (n & 63);
        float xv[64];
        #pragma unroll
        for (int c = 0; c < 64; ++c) xv[c] = x[gx + (long)c * 4096];
        int k1 = bki1[nl], k2 = bki2[nl];
        if (k2 != k1) {   // exact fp32 re-decision (matches ref-proven R2 ordering)
            const float* e1 = cbg + (k1 << 6);
            const float* e2 = cbg + (k2 << 6);
            float a0=0,a1=0,a2=0,a3=0, c0=0,c1=0,c2=0,c3=0;
            #pragma unroll
            for (int j = 0; j < 16; ++j) {
                a0 = fmaf(xv[4*j+0], e1[4*j+0], a0);
                a1 = fmaf(xv[4*j+1], e1[4*j+1], a1);
                a2 = fmaf(xv[4*j+2], e1[4*j+2], a2);
                a3 = fmaf(xv[4*j+3], e1[4*j+3], a3);
                c0 = fmaf(xv[4*j+0], e2[4*j+0], c0);
                c1 = fmaf(xv[4*j+1], e2[4*j+1], c1);
                c2 = fmaf(xv[4*j+2], e2[4*j+2], c2);
                c3 = fmaf(xv[4*j+3], e2[4*j+3], c3);
            }
            float s1 = esq[k1] - 2.f * ((a0 + a1) + (a2 + a3));
            float s2 = esq[k2] - 2.f * ((c0 + c1) + (c2 + c3));
            if (s2 < s1 || (s2 == s1 && k2 < k1)) k1 = k2;
        }
        float lsum = 0.f;
        const float* qg = cbg + (k1 << 6);
        const int sb = k1 * 65;
        #pragma unroll
        for (int c = 0; c < 64; ++c) {
            float qc = qg[c], xc = xv[c];
            out[gx + (long)c * 4096] = xc + (qc - xc);   // ref arithmetic
            float d = xc - qc;
            lsum = fmaf(d, d, lsum);
            atomicAdd(&sums[sb + c], xc);
        }
        atomicAdd(&hist[k1], 1.0f);
        #pragma unroll
        for (int o = 32; o > 0; o >>= 1) lsum += __shfl_down(lsum, o, 64);
        if (lane == 0) red[wv] = lsum;
    }
    __syncthreads();

    // ---- flush to global slab ----
    if (atomic_mode) {
        float* slab = slab_base;
        for (int i = tid; i < 32768; i += 512) {
            float v = sums[(i >> 6) * 65 + (i & 63)];
            if (v != 0.f) atomicAdd(&slab[i], v);
        }
        { float v = hist[tid]; if (v != 0.f) atomicAdd(&slab[32768 + tid], v); }
        if (tid == 0) {
            float l = 0.f;
            #pragma unroll
            for (int i = 0; i < 8; ++i) l += red[i];
            atomicAdd(&slab[33280], l);
        }
    } else {
        float* slab = slab_base + (long)blockIdx.x * SLAB_STRIDE;
        #pragma unroll 4
        for (int i = tid; i < 32768; i += 512)
            slab[i] = sums[(i >> 6) * 65 + (i & 63)];
        slab[32768 + tid] = hist[tid];
        if (tid == 0) {
            float l = 0.f;
            #pragma unroll
            for (int i = 0; i < 8; ++i) l += red[i];
            slab[33280] = l;
        }
    }
}

__global__ void __launch_bounds__(512)
vq_scalars(const float* __restrict__ slab_base, const float* __restrict__ ema_cs,
           float* __restrict__ smoothed, float* __restrict__ out_scalars, int nslab) {
    __shared__ float s_red[32];
    const int tid = threadIdx.x;          // tid == code k
    float cnt = 0.f;
    #pragma unroll 8
    for (int s = 0; s < nslab; ++s) cnt += slab_base[(long)s * SLAB_STRIDE + 32768 + tid];
    float ncs = 0.99f * ema_cs[tid] + 0.01f * cnt;

    float v1 = ncs;
    float v2 = (cnt > 0.f) ? 1.f : 0.f;
    float v3 = (tid < nslab) ? slab_base[(long)tid * SLAB_STRIDE + 33280] : 0.f;
    #pragma unroll
    for (int o = 32; o > 0; o >>= 1) {
        v1 += __shfl_down(v1, o, 64);
        v2 += __shfl_down(v2, o, 64);
        v3 += __shfl_down(v3, o, 64);
    }
    const int wv = tid >> 6;
    if ((tid & 63) == 0) { s_red[wv] = v1; s_red[wv + 8] = v2; s_red[wv + 16] = v3; }
    __syncthreads();
    if (tid == 0) {
        float n = 0.f, uq = 0.f, l = 0.f;
        #pragma unroll
        for (int i = 0; i < 8; ++i) { n += s_red[i]; uq += s_red[i + 8]; l += s_red[i + 16]; }
        s_red[24] = n;
        out_scalars[0] = l / 8388608.f;
        out_scalars[1] = uq;
    }
    __syncthreads();
    float n = s_red[24];
    smoothed[tid] = (ncs + 1e-5f) / (n + 512.f * 1e-5f) * n;
}

__global__ void __launch_bounds__(256)
vq_codebook(const float* __restrict__ slab_base, const float* __restrict__ ema_w,
            const float* __restrict__ smoothed, float* __restrict__ out_cb, int nslab) {
    const int e = blockIdx.x * 256 + threadIdx.x;
    float s = 0.f;
    #pragma unroll 8
    for (int sl = 0; sl < nslab; ++sl) s += slab_base[(long)sl * SLAB_STRIDE + e];
    float nw = 0.99f * ema_w[e] + 0.01f * s;
    out_cb[e] = nw / smoothed[e >> 6];
}

extern "C" void kernel_launch(void* const* d_in, const int* in_sizes, int n_in,
                              void* d_out, int out_size, void* d_ws, size_t ws_size,
                              hipStream_t stream) {
    const float* x      = (const float*)d_in[0];
    const float* cb     = (const float*)d_in[1];
    const float* ema_cs = (const float*)d_in[2];
    const float* ema_w  = (const float*)d_in[3];

    float* out     = (float*)d_out;
    float* scalars = out + 8388608;
    float* out_cb  = out + 8388610;
    float* ws      = (float*)d_ws;

    // ws: [slabs nslab*SLAB_STRIDE][smoothed 512][esq 512][cbF 32768 floats-worth]
    const size_t fast_floats = (size_t)NSLAB_FAST * SLAB_STRIDE + 512 + 512 + 32768;
    int nslab, atomic_mode;
    if (ws_size >= fast_floats * sizeof(float)) { nslab = NSLAB_FAST; atomic_mode = 0; }
    else                                        { nslab = 1;          atomic_mode = 1; }

    float* smoothed = ws + (size_t)nslab * SLAB_STRIDE;
    float* esq      = smoothed + 512;
    char*  cbF      = (char*)(esq + 512);

    if (atomic_mode) {
        hipMemsetAsync(d_ws, 0, (size_t)SLAB_STRIDE * sizeof(float), stream);
    }

    vq_prep<<<1, 512, 0, stream>>>(cb, esq, cbF);
    const size_t lds_bytes = (size_t)LDS_FLOATS * sizeof(float);   // 141,376 B
    vq_assign<<<256, 512, lds_bytes, stream>>>(x, cb, esq, cbF, out, ws, atomic_mode);
    vq_scalars<<<1, 512, 0, stream>>>(ws, ema_cs, smoothed, scalars, nslab);
    vq_codebook<<<128, 256, 0, stream>>>(ws, ema_w, smoothed, out_cb, nslab);
}

// Round 4
// 128.705 us; speedup vs baseline: 3.0453x; 1.1706x over previous
//
#include <hip/hip_runtime.h>

// VQ-VAE vector quantizer: B=32,C=64,H=64,W=64, K=512, DECAY=0.99, EPS=1e-5
// N = 131072 vectors, dim 64.
// R4: vq_assign = MFMA argmin (bf16 hi/lo 4-term) + refine + LDS segment sums only.
// out/loss/q-gather moved to high-occupancy vq_post (float4 gather); slab reduce
// parallelized into vq_post; prep parallelized. B-frags load direct from global.

typedef __attribute__((ext_vector_type(8))) short bf16x8;
typedef __attribute__((ext_vector_type(16))) float f32x16;

#define KCODES 512
#define SLAB_STRIDE 33280     // per-block slab: 32768 sums + 512 counts
#define NSLAB 256

// vq_assign LDS layout (floats)
#define OFF_HIST 33280        // 512
#define OFF_ESQ  33792        // 512
#define OFF_BK1  34304        // 512
#define OFF_BK2  34816        // 512
#define LDS_FLOATS 35328      // 141,312 B < 160 KiB

#define MFMA32 __builtin_amdgcn_mfma_f32_32x32x16_bf16

__device__ __forceinline__ unsigned short f2bf(float f) {
    unsigned u = __float_as_uint(f);
    return (unsigned short)((u + 0x7fffu + ((u >> 16) & 1u)) >> 16);
}
__device__ __forceinline__ float bf2f(unsigned short h) {
    return __uint_as_float(((unsigned)h) << 16);
}

// ---- prep: esq + fragment-major bf16 hi/lo codebook; 8 blocks, LDS transpose ----
// cbF unit u = (cs*2+hh)*512 + k, 32 bytes: [hi bf16x8 | lo bf16x8], c = cs*16+hh*8+j
__global__ void __launch_bounds__(512)
vq_prep(const float* __restrict__ cb, float* __restrict__ esq, char* __restrict__ cbF) {
    __shared__ float tile[64 * 65];
    const int tid = threadIdx.x;
    const int k0  = blockIdx.x * 64;
    #pragma unroll
    for (int i = tid; i < 4096; i += 512)
        tile[(i >> 6) * 65 + (i & 63)] = cb[k0 * 64 + i];   // coalesced
    __syncthreads();
    const int unit = tid >> 6;          // 0..7 == cs*2+hh
    const int kl   = tid & 63;
    const float* row = tile + kl * 65;
    const int cbase = (unit >> 1) * 16 + (unit & 1) * 8;
    bf16x8 h8, l8;
    #pragma unroll
    for (int j = 0; j < 8; ++j) {
        float e = row[cbase + j];
        unsigned short hb = f2bf(e);
        float lo = e - bf2f(hb);
        h8[j] = (short)hb;
        l8[j] = (short)f2bf(lo);
    }
    char* p = cbF + (size_t)((unit * 512 + k0 + kl) * 32);
    *(bf16x8*)p = h8;
    *(bf16x8*)(p + 16) = l8;
    if (unit == 0) {
        float s = 0.f;
        #pragma unroll
        for (int c = 0; c < 64; ++c) { float v = row[c]; s = fmaf(v, v, s); }
        esq[k0 + kl] = s;
    }
}

__device__ __forceinline__ void loadA(const char* __restrict__ cbF, int hh, int code,
                                      bf16x8* A) {
    #pragma unroll
    for (int cs = 0; cs < 4; ++cs) {
        const char* p = cbF + (size_t)(((cs * 2 + hh) * 512 + code) * 32);
        A[2 * cs]     = *(const bf16x8*)p;        // hi
        A[2 * cs + 1] = *(const bf16x8*)(p + 16); // lo
    }
}

// top-2 update; kq wave-uniform, strict < keeps first (ascending kq)
__device__ __forceinline__ void upd(float s, int kq, float& b1, int& q1, float& b2, int& q2) {
    bool t1 = s < b1;
    bool t2 = s < b2;
    float nb2 = t1 ? b1 : (t2 ? s : b2);
    int   nq2 = t1 ? q1 : (t2 ? kq : q2);
    b2 = nb2; q2 = nq2;
    b1 = t1 ? s : b1;
    q1 = t1 ? kq : q1;
}

__global__ void __launch_bounds__(512, 1)
vq_assign(const float* __restrict__ x, const float* __restrict__ cbg,
          const float* __restrict__ esqg, const char* __restrict__ cbF,
          unsigned short* __restrict__ bkg, float* __restrict__ slab_base) {
    extern __shared__ float lds[];
    float* sums = lds;                       // 512 x 65 (phase 2)
    float* hist = lds + OFF_HIST;
    float* esq  = lds + OFF_ESQ;
    int*   bki1 = (int*)(lds + OFF_BK1);
    int*   bki2 = (int*)(lds + OFF_BK2);
    const int tid  = threadIdx.x;
    const int lane = tid & 63;
    const int wv   = tid >> 6;        // 0..7
    const int l31  = lane & 31;
    const int hh   = lane >> 5;
    const int n0   = blockIdx.x * 512;

    esq[tid] = esqg[tid];

    // ---- B fragments (x, hi/lo -2x) direct from global, coalesced ----
    bf16x8 B0h[4], B0l[4], B1h[4], B1l[4];
    #pragma unroll
    for (int ct = 0; ct < 2; ++ct) {
        const int n  = n0 + wv * 64 + ct * 32 + l31;
        const int bb = n >> 12, h = (n >> 6) & 63;
        const long gx = (long)bb * 262144 + (long)h * 64 + (n & 63);
        #pragma unroll
        for (int cs = 0; cs < 4; ++cs) {
            bf16x8 h8, l8;
            #pragma unroll
            for (int j = 0; j < 8; ++j) {
                float v = x[gx + (long)(cs * 16 + hh * 8 + j) * 4096];
                float m2 = -2.f * v;
                unsigned short hb = f2bf(m2);
                float lo = m2 - bf2f(hb);
                h8[j] = (short)hb;
                l8[j] = (short)f2bf(lo);
            }
            if (ct == 0) { B0h[cs] = h8; B0l[cs] = l8; }
            else         { B1h[cs] = h8; B1l[cs] = l8; }
        }
    }
    __syncthreads();                  // esq ready

    // ---- K loop: 16 tiles of 32 codes, 2-deep A prefetch (R3-proven core) ----
    float b1[2] = {3.4e38f, 3.4e38f}, b2[2] = {3.4e38f, 3.4e38f};
    int   q1[2] = {0, 0},             q2[2] = {0, 0};
    bf16x8 A0[8], A1[8];
    loadA(cbF, hh, l31, A0);
    #pragma unroll 1
    for (int kt = 0; kt < 16; kt += 2) {
        loadA(cbF, hh, (kt + 1) * 32 + l31, A1);
        {
            f32x16 acc0 = {}; f32x16 acc1 = {};
            #pragma unroll
            for (int cs = 0; cs < 4; ++cs) {
                acc0 = MFMA32(A0[2*cs],   B0h[cs], acc0, 0, 0, 0);
                acc0 = MFMA32(A0[2*cs+1], B0h[cs], acc0, 0, 0, 0);
                acc0 = MFMA32(A0[2*cs],   B0l[cs], acc0, 0, 0, 0);
                acc0 = MFMA32(A0[2*cs+1], B0l[cs], acc0, 0, 0, 0);
                acc1 = MFMA32(A0[2*cs],   B1h[cs], acc1, 0, 0, 0);
                acc1 = MFMA32(A0[2*cs+1], B1h[cs], acc1, 0, 0, 0);
                acc1 = MFMA32(A0[2*cs],   B1l[cs], acc1, 0, 0, 0);
                acc1 = MFMA32(A0[2*cs+1], B1l[cs], acc1, 0, 0, 0);
            }
            #pragma unroll
            for (int g = 0; g < 4; ++g) {
                float4 e4 = *(const float4*)(esq + kt * 32 + 4 * hh + 8 * g);
                const float ev[4] = {e4.x, e4.y, e4.z, e4.w};
                #pragma unroll
                for (int r = 0; r < 4; ++r) {
                    int kq = kt * 32 + 8 * g + r;
                    upd(ev[r] + acc0[4*g+r], kq, b1[0], q1[0], b2[0], q2[0]);
                    upd(ev[r] + acc1[4*g+r], kq, b1[1], q1[1], b2[1], q2[1]);
                }
            }
        }
        if (kt + 2 < 16) loadA(cbF, hh, (kt + 2) * 32 + l31, A0);
        {
            f32x16 acc0 = {}; f32x16 acc1 = {};
            #pragma unroll
            for (int cs = 0; cs < 4; ++cs) {
                acc0 = MFMA32(A1[2*cs],   B0h[cs], acc0, 0, 0, 0);
                acc0 = MFMA32(A1[2*cs+1], B0h[cs], acc0, 0, 0, 0);
                acc0 = MFMA32(A1[2*cs],   B0l[cs], acc0, 0, 0, 0);
                acc0 = MFMA32(A1[2*cs+1], B0l[cs], acc0, 0, 0, 0);
                acc1 = MFMA32(A1[2*cs],   B1h[cs], acc1, 0, 0, 0);
                acc1 = MFMA32(A1[2*cs+1], B1h[cs], acc1, 0, 0, 0);
                acc1 = MFMA32(A1[2*cs],   B1l[cs], acc1, 0, 0, 0);
                acc1 = MFMA32(A1[2*cs+1], B1l[cs], acc1, 0, 0, 0);
            }
            #pragma unroll
            for (int g = 0; g < 4; ++g) {
                float4 e4 = *(const float4*)(esq + (kt + 1) * 32 + 4 * hh + 8 * g);
                const float ev[4] = {e4.x, e4.y, e4.z, e4.w};
                #pragma unroll
                for (int r = 0; r < 4; ++r) {
                    int kq = (kt + 1) * 32 + 8 * g + r;
                    upd(ev[r] + acc0[4*g+r], kq, b1[0], q1[0], b2[0], q2[0]);
                    upd(ev[r] + acc1[4*g+r], kq, b1[1], q1[1], b2[1], q2[1]);
                }
            }
        }
    }

    // ---- merge lane-halves (true k = kq + 4*hh), top-2 kept for refine ----
    #pragma unroll
    for (int ct = 0; ct < 2; ++ct) {
        float mb1 = b1[ct], mb2 = b2[ct];
        int   mk1 = q1[ct] + 4 * hh, mk2 = q2[ct] + 4 * hh;
        float ob1 = __shfl_xor(mb1, 32, 64); int ok1 = __shfl_xor(mk1, 32, 64);
        float ob2 = __shfl_xor(mb2, 32, 64); int ok2 = __shfl_xor(mk2, 32, 64);
        bool t = (ob1 < mb1) || (ob1 == mb1 && ok1 < mk1);
        float w1 = t ? ob1 : mb1;  int wk1 = t ? ok1 : mk1;
        float l1 = t ? mb1 : ob1;  int lk1 = t ? mk1 : ok1;
        float w2c = t ? ob2 : mb2; int wk2c = t ? ok2 : mk2;
        bool t2 = (w2c < l1) || (w2c == l1 && wk2c < lk1);
        float w2 = t2 ? w2c : l1;  int wk2 = t2 ? wk2c : lk1;
        if (hh == 0) {
            int nl = wv * 64 + ct * 32 + l31;
            bki1[nl] = wk1;
            bki2[nl] = (w2 - w1 < 1e-3f) ? wk2 : wk1;   // refine only near-ties
        }
    }

    // ---- zero phase-2 accumulators ----
    #pragma unroll 4
    for (int i = tid; i < 33792; i += 512) lds[i] = 0.f;
    __syncthreads();

    // ---- phase 2: refine + index export + segment sums ----
    {
        const int n  = n0 + tid;
        const int bb = n >> 12, h = (n >> 6) & 63;
        const long gx = (long)bb * 262144 + (long)h * 64 + (n & 63);
        float xv[64];
        #pragma unroll
        for (int c = 0; c < 64; ++c) xv[c] = x[gx + (long)c * 4096];
        int k1 = bki1[tid], k2 = bki2[tid];
        if (k2 != k1) {   // exact fp32 re-decision (R2-proven ordering), float4 loads
            const float4* e1 = (const float4*)(cbg + (k1 << 6));
            const float4* e2 = (const float4*)(cbg + (k2 << 6));
            float a0=0,a1=0,a2=0,a3=0, c0=0,c1=0,c2=0,c3=0;
            #pragma unroll
            for (int j = 0; j < 16; ++j) {
                float4 ea = e1[j], eb = e2[j];
                a0 = fmaf(xv[4*j+0], ea.x, a0);
                a1 = fmaf(xv[4*j+1], ea.y, a1);
                a2 = fmaf(xv[4*j+2], ea.z, a2);
                a3 = fmaf(xv[4*j+3], ea.w, a3);
                c0 = fmaf(xv[4*j+0], eb.x, c0);
                c1 = fmaf(xv[4*j+1], eb.y, c1);
                c2 = fmaf(xv[4*j+2], eb.z, c2);
                c3 = fmaf(xv[4*j+3], eb.w, c3);
            }
            float s1 = esq[k1] - 2.f * ((a0 + a1) + (a2 + a3));
            float s2 = esq[k2] - 2.f * ((c0 + c1) + (c2 + c3));
            if (s2 < s1 || (s2 == s1 && k2 < k1)) k1 = k2;
        }
        bkg[n] = (unsigned short)k1;
        const int sb = k1 * 65;
        #pragma unroll
        for (int c = 0; c < 64; ++c) atomicAdd(&sums[sb + c], xv[c]);
        atomicAdd(&hist[k1], 1.0f);
    }
    __syncthreads();

    // ---- flush per-block slab (coalesced) ----
    float* slab = slab_base + (long)blockIdx.x * SLAB_STRIDE;
    #pragma unroll 4
    for (int i = tid; i < SLAB_STRIDE; i += 512) {
        float v = (i < 32768) ? sums[(i >> 6) * 65 + (i & 63)] : hist[i - 32768];
        slab[i] = v;
    }
}

// blocks 0..511: out + loss; 512..1023: slab sums reduce; 1024..1031: hist reduce
__global__ void __launch_bounds__(256)
vq_post(const float* __restrict__ x, const float* __restrict__ cbg,
        const unsigned short* __restrict__ bkg, const float* __restrict__ slabs,
        float* __restrict__ red_sums, float* __restrict__ red_hist,
        float* __restrict__ acc_loss, float* __restrict__ out) {
    const int bid = blockIdx.x;
    const int tid = threadIdx.x;
    if (bid < 512) {
        const int n  = bid * 256 + tid;              // lane = w: coalesced
        const int bb = n >> 12, h = (n >> 6) & 63;
        const long gx = (long)bb * 262144 + (long)h * 64 + (n & 63);
        const int k1 = bkg[n];
        const float4* q4 = (const float4*)(cbg + (k1 << 6));
        float lsum = 0.f;
        #pragma unroll
        for (int j = 0; j < 16; ++j) {
            float4 q = q4[j];
            const float qv[4] = {q.x, q.y, q.z, q.w};
            #pragma unroll
            for (int r = 0; r < 4; ++r) {
                const int c = 4 * j + r;
                float xc = x[gx + (long)c * 4096];
                float qc = qv[r];
                out[gx + (long)c * 4096] = xc + (qc - xc);   // ref arithmetic
                float d = xc - qc;
                lsum = fmaf(d, d, lsum);
            }
        }
        #pragma unroll
        for (int o = 32; o > 0; o >>= 1) lsum += __shfl_down(lsum, o, 64);
        __shared__ float sred[4];
        if ((tid & 63) == 0) sred[tid >> 6] = lsum;
        __syncthreads();
        if (tid == 0) atomicAdd(acc_loss, (sred[0] + sred[1]) + (sred[2] + sred[3]));
    } else if (bid < 1024) {
        const int e0 = (bid - 512) * 64;
        const int e  = e0 + (tid & 63);
        const int sg = tid >> 6;
        float s = 0.f;
        #pragma unroll 8
        for (int sl = sg; sl < NSLAB; sl += 4) s += slabs[(long)sl * SLAB_STRIDE + e];
        __shared__ float part[4][64];
        part[sg][tid & 63] = s;
        __syncthreads();
        if (tid < 64)
            red_sums[e0 + tid] = (part[0][tid] + part[1][tid]) + (part[2][tid] + part[3][tid]);
    } else {
        const int k0 = (bid - 1024) * 64;
        const int k  = k0 + (tid & 63);
        const int sg = tid >> 6;
        float s = 0.f;
        #pragma unroll 8
        for (int sl = sg; sl < NSLAB; sl += 4) s += slabs[(long)sl * SLAB_STRIDE + 32768 + k];
        __shared__ float part2[4][64];
        part2[sg][tid & 63] = s;
        __syncthreads();
        if (tid < 64)
            red_hist[k0 + tid] = (part2[0][tid] + part2[1][tid]) + (part2[2][tid] + part2[3][tid]);
    }
}

__global__ void __launch_bounds__(512)
vq_scalars(const float* __restrict__ red_hist, const float* __restrict__ acc_loss,
           const float* __restrict__ ema_cs, float* __restrict__ smoothed,
           float* __restrict__ out_scalars) {
    __shared__ float s_red[17];
    const int tid = threadIdx.x;          // tid == code k
    float cnt = red_hist[tid];
    float ncs = 0.99f * ema_cs[tid] + 0.01f * cnt;
    float v1 = ncs;
    float v2 = (cnt > 0.f) ? 1.f : 0.f;
    #pragma unroll
    for (int o = 32; o > 0; o >>= 1) {
        v1 += __shfl_down(v1, o, 64);
        v2 += __shfl_down(v2, o, 64);
    }
    const int wv = tid >> 6;
    if ((tid & 63) == 0) { s_red[wv] = v1; s_red[wv + 8] = v2; }
    __syncthreads();
    if (tid == 0) {
        float n = 0.f, uq = 0.f;
        #pragma unroll
        for (int i = 0; i < 8; ++i) { n += s_red[i]; uq += s_red[i + 8]; }
        s_red[16] = n;
        out_scalars[0] = acc_loss[0] / 8388608.f;
        out_scalars[1] = uq;
    }
    __syncthreads();
    float n = s_red[16];
    smoothed[tid] = (ncs + 1e-5f) / (n + 512.f * 1e-5f) * n;
}

__global__ void __launch_bounds__(128)
vq_codebook(const float* __restrict__ red_sums, const float* __restrict__ ema_w,
            const float* __restrict__ smoothed, float* __restrict__ out_cb) {
    const int e = blockIdx.x * 128 + threadIdx.x;      // 0..32767
    float nw = 0.99f * ema_w[e] + 0.01f * red_sums[e];
    out_cb[e] = nw / smoothed[e >> 6];
}

extern "C" void kernel_launch(void* const* d_in, const int* in_sizes, int n_in,
                              void* d_out, int out_size, void* d_ws, size_t ws_size,
                              hipStream_t stream) {
    const float* x      = (const float*)d_in[0];
    const float* cb     = (const float*)d_in[1];
    const float* ema_cs = (const float*)d_in[2];
    const float* ema_w  = (const float*)d_in[3];

    float* out     = (float*)d_out;
    float* scalars = out + 8388608;
    float* out_cb  = out + 8388610;
    float* ws      = (float*)d_ws;

    // ws layout (floats):
    float* slabs    = ws;                                   // 256 * 33280
    float* red_sums = ws + (size_t)NSLAB * SLAB_STRIDE;     // 32768
    float* red_hist = red_sums + 32768;                     // 512
    float* smoothed = red_hist + 512;                       // 512
    float* esq      = smoothed + 512;                       // 512
    float* acc_loss = esq + 512;                            // 64 (1 used)
    char*  cbF      = (char*)(acc_loss + 64);               // 131072 B
    unsigned short* bkg = (unsigned short*)(cbF + 131072);  // 131072 ushort
    // total ~34.6 MB (< R3-proven ws capacity)

    hipMemsetAsync(acc_loss, 0, sizeof(float), stream);
    vq_prep<<<8, 512, 0, stream>>>(cb, esq, cbF);
    const size_t lds_bytes = (size_t)LDS_FLOATS * sizeof(float);   // 141,312 B
    vq_assign<<<256, 512, lds_bytes, stream>>>(x, cb, esq, cbF, bkg, slabs);
    vq_post<<<1032, 256, 0, stream>>>(x, cb, bkg, slabs, red_sums, red_hist, acc_loss, out);
    vq_scalars<<<1, 512, 0, stream>>>(red_hist, acc_loss, ema_cs, smoothed, scalars);
    vq_codebook<<<256, 128, 0, stream>>>(red_sums, ema_w, smoothed, out_cb);
}